// Round 1
// baseline (76.087 us; speedup 1.0000x reference)
//
#include <hip/hip_runtime.h>
#include <stdint.h>

// GCMConv on MI355X. Data model (verified rounds 0-3):
//   x      : float32 (1,16384,8,3,3,2)  — complex pair = v2f
//   weight : float32 (4,9,33)
//   out    : float32 (1,16384,8,3,3,2)
//
// M-factorization (16 threads/site: u=out-channel, g=quarter):
//   M[u,v] = sum_w16 ( wt[u,v,w16] t[w16] + wt[u,v,16+w16] t[w16]^+ ) + wt[u,v,32] I
//   out[u] = sum_v w_full[v] @ M[u,v];  thread (u,g) builds M[u,g], M[u,4+g];
//   cc gets the v=8 (identity-channel) share from the thread's own w16 quarter.
//
// Round-14 "fewer LDS issues + pinned occupancy tier":
//  - weights packed in LDS as float4 {a1,b1,a2,b2}[(u*4+g)*17+w16] -> ONE
//    ds_read_b128 per main-loop iter (was 4x ds_read_b32); stride 17 pads the
//    b128 reads to the 2-pass minimum (16 uniq addrs x 16B = 256B / 128B banks)
//  - cc weights packed float2 [u*17+w16] -> one b64/iter, bank-conflict-free
//  - w=32 identity scalars read from GLOBAL right after the barrier (L2-hot,
//    used only in the epilogue -> latency fully hidden); full wsm staging gone
//  - #pragma unroll 2 on main/cc loops: two iterations' LDS reads batch, FMAs
//    of iter k overlap loads of iter k+1 (halves exposed LDS latency)
//  - __launch_bounds__(256,4): pin the <=128-VGPR / 4-waves-per-SIMD tier
//    (live set ~110 floats at peak; 2-waves tier would halve latency hiding)

typedef float v2f __attribute__((ext_vector_type(2)));

#define SPB 16            // sites per block
#define TPB 256           // 16 threads per site
#define NSITES 16384
#define TS_TILE 10        // v2f per tile (9 + 1 pad, 80 B -> 16B-aligned tiles)
#define TS2_SITE 164      // v2f per site: 16*10 + 4 spare

#if defined(__has_builtin)
#if __has_builtin(__builtin_elementwise_fma)
#define HAVE_EW_FMA 1
#endif
#endif

__device__ __forceinline__ v2f pkfma(v2f a, v2f b, v2f c){
#ifdef HAVE_EW_FMA
    return __builtin_elementwise_fma(a, b, c);
#else
    v2f r; r.x = fmaf(a.x, b.x, c.x); r.y = fmaf(a.y, b.y, c.y); return r;
#endif
}
__device__ __forceinline__ v2f spl(float s){ return (v2f){s, s}; }
__device__ __forceinline__ v2f pn (float s){ return (v2f){s, -s}; }
__device__ __forceinline__ v2f np (float s){ return (v2f){-s, s}; }
__device__ __forceinline__ v2f swp(v2f a){ return __builtin_shufflevector(a, a, 1, 0); }
__device__ __forceinline__ v2f zero2(){ return (v2f){0.f, 0.f}; }

__device__ __forceinline__ int neigh(int s, int a){
    // dims (8,8,16,16): d3 bits[0:4), d2 bits[4:8), d1 bits[8:11), d0 bits[11:14)
    if (a == 3) return (s & ~15)        | ((s + 1)    & 15);
    if (a == 2) return (s & ~(15 << 4)) | ((s + 16)   & (15 << 4));
    if (a == 1) return (s & ~(7 << 8))  | ((s + 256)  & (7 << 8));
    return              (s & ~(7 << 11))| ((s + 2048) & (7 << 11));
}

// load one 9-v2f tile via 4x ds_read_b128 + 1x ds_read_b64
__device__ __forceinline__ void load_tile(v2f* tc, const v2f* tp){
    const float4* tp4 = (const float4*)tp;
    float4 q0 = tp4[0], q1 = tp4[1], q2 = tp4[2], q3 = tp4[3];
    tc[0] = (v2f){q0.x, q0.y}; tc[1] = (v2f){q0.z, q0.w};
    tc[2] = (v2f){q1.x, q1.y}; tc[3] = (v2f){q1.z, q1.w};
    tc[4] = (v2f){q2.x, q2.y}; tc[5] = (v2f){q2.z, q2.w};
    tc[6] = (v2f){q3.x, q3.y}; tc[7] = (v2f){q3.z, q3.w};
    tc[8] = tp[8];
}

__global__ __launch_bounds__(TPB, 4)
void gcm_fused(const float* __restrict__ xp,
               const float* __restrict__ wgt,
               float* __restrict__ outp)
{
    __shared__ alignas(16) v2f    lt[SPB * TS2_SITE];
    __shared__ alignas(16) float4 wpk[16 * 17];      // [(u*4+g)*17 + w16] = {a1,b1,a2,b2}
    __shared__ alignas(8)  float2 wpk8[4 * 17 + 16]; // [u*17 + w16]       = {c8,d8}
    const v2f* x2 = (const v2f*)xp;
    v2f* o2 = (v2f*)outp;

    const int tid = threadIdx.x;
    const int g   = tid & 3;            // lane bits 0-1 -> shfl_xor reduction
    const int u   = (tid >> 2) & 3;     // output channel / phase1 axis
    const int sl  = tid >> 4;           // site within block
    const int s   = blockIdx.x * SPB + sl;

    // stage packed weights to LDS (one float4 per thread; first 64 also float2)
    {
        const int u_ = tid >> 6, g_ = (tid >> 4) & 3, w_ = tid & 15;
        const float* wu_ = wgt + u_ * 297;
        wpk[(u_ * 4 + g_) * 17 + w_] =
            make_float4(wu_[g_ * 33 + w_],       wu_[g_ * 33 + 16 + w_],
                        wu_[(4 + g_) * 33 + w_], wu_[(4 + g_) * 33 + 16 + w_]);
        if (tid < 64){
            const int uu = tid >> 4, ww = tid & 15;
            const float* w8 = wgt + uu * 297 + 264;   // [u][8][*]
            wpk8[uu * 17 + ww] = make_float2(w8[ww], w8[16 + ww]);
        }
    }

    // ============ phase 1: one transport per thread: t[u*4+g] = U_u W_g(s+u^) U_u^+
    {
        v2f uc[9], wc[9];
        {
            const v2f* up = x2 + (s * 8 + u) * 9;
            #pragma unroll
            for (int e = 0; e < 9; e++) uc[e] = up[e];
        }
        const int sn = neigh(s, u);
        {
            const v2f* wp = x2 + (sn * 8 + 4 + g) * 9;
            #pragma unroll
            for (int e = 0; e < 9; e++) wc[e] = wp[e];
        }
        // T1 = U * W
        v2f t1[9];
        #pragma unroll
        for (int r = 0; r < 3; r++){
            #pragma unroll
            for (int k = 0; k < 3; k++){
                v2f acc = zero2();
                #pragma unroll
                for (int j = 0; j < 3; j++){
                    v2f a_ = uc[r*3+j], b_ = wc[j*3+k];
                    acc = pkfma(spl(a_.x), b_, acc);
                    acc = pkfma(np(a_.y), swp(b_), acc);
                }
                t1[r*3+k] = acc;
            }
        }
        // T = T1 * U^+ : T[r,k] = sum_j T1[r,j] * conj(U[k,j]); b128 writes
        v2f tt[9];
        #pragma unroll
        for (int r = 0; r < 3; r++){
            #pragma unroll
            for (int k = 0; k < 3; k++){
                v2f acc = zero2();
                #pragma unroll
                for (int j = 0; j < 3; j++){
                    v2f a_ = t1[r*3+j], b_ = uc[k*3+j];
                    acc = pkfma(pn(a_.x), b_, acc);
                    acc = pkfma(spl(a_.y), swp(b_), acc);
                }
                tt[r*3+k] = acc;
            }
        }
        v2f* dst = &lt[sl * TS2_SITE + (u * 4 + g) * TS_TILE];
        float4* dst4 = (float4*)dst;
        dst4[0] = make_float4(tt[0].x, tt[0].y, tt[1].x, tt[1].y);
        dst4[1] = make_float4(tt[2].x, tt[2].y, tt[3].x, tt[3].y);
        dst4[2] = make_float4(tt[4].x, tt[4].y, tt[5].x, tt[5].y);
        dst4[3] = make_float4(tt[6].x, tt[6].y, tt[7].x, tt[7].y);
        dst[8] = tt[8];
    }
    __syncthreads();

    // ============ phase 2 ============
    // w=32 identity scalars straight from global (L2-hot; consumed only in the
    // epilogue, so ~200cy latency is fully hidden under the main loop)
    const float* wub = wgt + u * 297;
    const float wA32 = wub[g * 33 + 32];
    const float wB32 = wub[(4 + g) * 33 + 32];
    const float w832 = wub[296];

    // pass-through copy of u channels (one quarter of lanes)
    if (g == 1){
        const v2f* src = x2 + (s * 8 + u) * 9;
        v2f* dst = o2 + (s * 8 + u) * 9;
        #pragma unroll
        for (int e = 0; e < 9; e++) dst[e] = src[e];
    }

    v2f M1[9], M2[9];
    #pragma unroll
    for (int e = 0; e < 9; e++){ M1[e] = zero2(); M2[e] = zero2(); }

    const v2f* tbase = &lt[sl * TS2_SITE];
    const int ug17 = (u * 4 + g) * 17;

    // ---- main loop: M1/M2 only; w16 uniform across lanes (broadcast LDS reads)
    // one b128 weight read/iter; unroll 2 so iter k FMAs cover iter k+1 loads
    #pragma unroll 2
    for (int w16 = 0; w16 < 16; w16++){
        v2f tc[9];
        load_tile(tc, tbase + w16 * TS_TILE);
        const float4 wq = wpk[ug17 + w16];
        const float a1 = wq.x, b1 = wq.y, a2 = wq.z, b2 = wq.w;
        #pragma unroll
        for (int i = 0; i < 3; i++){
            #pragma unroll
            for (int j = 0; j < 3; j++){
                const int e = i*3+j, eT = j*3+i;
                M1[e] = pkfma(spl(a1), tc[e],  M1[e]);
                M1[e] = pkfma(pn(b1),  tc[eT], M1[e]);
                M2[e] = pkfma(spl(a2), tc[e],  M2[e]);
                M2[e] = pkfma(pn(b2),  tc[eT], M2[e]);
            }
        }
    }

    // ---- cc: v=8 share over this thread's own quarter (w16 = 4g+it)
    v2f cc[9];
    #pragma unroll
    for (int e = 0; e < 9; e++) cc[e] = zero2();
    #pragma unroll 2
    for (int it = 0; it < 4; it++){
        const int w16 = g * 4 + it;
        v2f tc[9];
        load_tile(tc, tbase + w16 * TS_TILE);
        const float2 w8 = wpk8[u * 17 + w16];
        const float c8 = w8.x, d8 = w8.y;
        #pragma unroll
        for (int i = 0; i < 3; i++){
            #pragma unroll
            for (int j = 0; j < 3; j++){
                const int e = i*3+j, eT = j*3+i;
                cc[e] = pkfma(spl(c8), tc[e],  cc[e]);
                cc[e] = pkfma(pn(d8),  tc[eT], cc[e]);
            }
        }
    }

    // ---- identity (w=32) contributions to the diagonals
    {
        M1[0].x += wA32; M1[4].x += wA32; M1[8].x += wA32;
        M2[0].x += wB32; M2[4].x += wB32; M2[8].x += wB32;
        if (g == 0){
            cc[0].x += w832; cc[4].x += w832; cc[8].x += w832;
        }
    }

    // ---- wg loaded late (R12: early-issue neutral; late keeps loop pressure low)
    v2f wg[9];
    {
        const v2f* wp = x2 + (s * 8 + 4 + g) * 9;
        #pragma unroll
        for (int e = 0; e < 9; e++) wg[e] = wp[e];
    }

    // ---- epilogue: cc += w[g] @ M1 + w[g]^+ @ M2
    #pragma unroll
    for (int i = 0; i < 3; i++){
        #pragma unroll
        for (int k = 0; k < 3; k++){
            v2f acc = cc[i*3+k];
            #pragma unroll
            for (int j = 0; j < 3; j++){
                v2f a_ = wg[i*3+j];
                v2f m  = M1[j*3+k];
                acc = pkfma(spl(a_.x), m,      acc);   // (ax*mr, ax*mi)
                acc = pkfma(np(a_.y),  swp(m), acc);   // (-ay*mi, ay*mr)
            }
            #pragma unroll
            for (int j = 0; j < 3; j++){
                v2f b_ = wg[j*3+i];                    // conj-transpose source
                v2f m  = M2[j*3+k];
                acc = pkfma(spl(b_.x), m,      acc);   // (bx*mr, bx*mi)
                acc = pkfma(pn(b_.y),  swp(m), acc);   // (by*mi, -by*mr)
            }
            cc[i*3+k] = acc;
        }
    }

    // --- reduce partials over g (lane bits 0-1) and store
    #pragma unroll
    for (int e = 0; e < 9; e++){
        cc[e].x += __shfl_xor(cc[e].x, 1);
        cc[e].x += __shfl_xor(cc[e].x, 2);
        cc[e].y += __shfl_xor(cc[e].y, 1);
        cc[e].y += __shfl_xor(cc[e].y, 2);
    }
    if (g == 0){
        v2f* dst = o2 + (s * 8 + 4 + u) * 9;
        #pragma unroll
        for (int e = 0; e < 9; e++) dst[e] = cc[e];
    }
}

extern "C" void kernel_launch(void* const* d_in, const int* in_sizes, int n_in,
                              void* d_out, int out_size, void* d_ws, size_t ws_size,
                              hipStream_t stream)
{
    const float* x = (const float*)d_in[0];
    const float* w = (const float*)d_in[1];
    float* out = (float*)d_out;
    dim3 grid(NSITES / SPB);
    dim3 block(TPB);
    hipLaunchKernelGGL(gcm_fused, grid, block, 0, stream, x, w, out);
}

// Round 2
// 74.238 us; speedup vs baseline: 1.0249x; 1.0249x over previous
//
#include <hip/hip_runtime.h>
#include <stdint.h>

// GCMConv on MI355X. Data model (verified rounds 0-3):
//   x      : float32 (1,16384,8,3,3,2)  — complex pair = v2f
//   weight : float32 (4,9,33)
//   out    : float32 (1,16384,8,3,3,2)
//
// M-factorization (16 threads/site: u=out-channel, g=quarter):
//   M[u,v] = sum_w16 ( wt[u,v,w16] t[w16] + wt[u,v,16+w16] t[w16]^+ ) + wt[u,v,32] I
//   out[u] = sum_v w_full[v] @ M[u,v];  thread (u,g) builds M[u,g], M[u,4+g];
//   cc gets the v=8 (identity-channel) share from the thread's own w16 quarter.
//
// Round-15 "kill the mid-kernel barrier":
//  - each site's 16 threads live in ONE wave (16-lane groups never straddle a
//    wave) -> the transported-tile exchange through LDS is wave-local. The
//    post-phase-1 __syncthreads (which forced vmcnt(0)+lgkmcnt(0) drain and
//    convoyed all 4 waves on the slowest HBM load) is replaced by a wave-local
//    s_waitcnt lgkmcnt(0) + sched_barrier(0). Waves desynchronize and hide
//    each other's phase-1 latency.
//  - ONE early __syncthreads right after weight staging (wpk/wpk8 are the only
//    cross-wave LDS data); phase-1 x loads are issued BEFORE staging so they
//    overlap it and the barrier wait.
//  - g==1 pass-through store reuses the uc registers (9 global loads saved).
//  - R14 carried: packed float4 weights (1 ds_read_b128/iter), unroll 2,
//    __launch_bounds__(256,4), 16B-aligned tiles.

typedef float v2f __attribute__((ext_vector_type(2)));

#define SPB 16            // sites per block
#define TPB 256           // 16 threads per site
#define NSITES 16384
#define TS_TILE 10        // v2f per tile (9 + 1 pad, 80 B -> 16B-aligned tiles)
#define TS2_SITE 164      // v2f per site: 16*10 + 4 spare

#if defined(__has_builtin)
#if __has_builtin(__builtin_elementwise_fma)
#define HAVE_EW_FMA 1
#endif
#endif

__device__ __forceinline__ v2f pkfma(v2f a, v2f b, v2f c){
#ifdef HAVE_EW_FMA
    return __builtin_elementwise_fma(a, b, c);
#else
    v2f r; r.x = fmaf(a.x, b.x, c.x); r.y = fmaf(a.y, b.y, c.y); return r;
#endif
}
__device__ __forceinline__ v2f spl(float s){ return (v2f){s, s}; }
__device__ __forceinline__ v2f pn (float s){ return (v2f){s, -s}; }
__device__ __forceinline__ v2f np (float s){ return (v2f){-s, s}; }
__device__ __forceinline__ v2f swp(v2f a){ return __builtin_shufflevector(a, a, 1, 0); }
__device__ __forceinline__ v2f zero2(){ return (v2f){0.f, 0.f}; }

__device__ __forceinline__ int neigh(int s, int a){
    // dims (8,8,16,16): d3 bits[0:4), d2 bits[4:8), d1 bits[8:11), d0 bits[11:14)
    if (a == 3) return (s & ~15)        | ((s + 1)    & 15);
    if (a == 2) return (s & ~(15 << 4)) | ((s + 16)   & (15 << 4));
    if (a == 1) return (s & ~(7 << 8))  | ((s + 256)  & (7 << 8));
    return              (s & ~(7 << 11))| ((s + 2048) & (7 << 11));
}

// load one 9-v2f tile via 4x ds_read_b128 + 1x ds_read_b64
__device__ __forceinline__ void load_tile(v2f* tc, const v2f* tp){
    const float4* tp4 = (const float4*)tp;
    float4 q0 = tp4[0], q1 = tp4[1], q2 = tp4[2], q3 = tp4[3];
    tc[0] = (v2f){q0.x, q0.y}; tc[1] = (v2f){q0.z, q0.w};
    tc[2] = (v2f){q1.x, q1.y}; tc[3] = (v2f){q1.z, q1.w};
    tc[4] = (v2f){q2.x, q2.y}; tc[5] = (v2f){q2.z, q2.w};
    tc[6] = (v2f){q3.x, q3.y}; tc[7] = (v2f){q3.z, q3.w};
    tc[8] = tp[8];
}

__global__ __launch_bounds__(TPB, 4)
void gcm_fused(const float* __restrict__ xp,
               const float* __restrict__ wgt,
               float* __restrict__ outp)
{
    __shared__ alignas(16) v2f    lt[SPB * TS2_SITE];
    __shared__ alignas(16) float4 wpk[16 * 17];      // [(u*4+g)*17 + w16] = {a1,b1,a2,b2}
    __shared__ alignas(8)  float2 wpk8[4 * 17 + 16]; // [u*17 + w16]       = {c8,d8}
    const v2f* x2 = (const v2f*)xp;
    v2f* o2 = (v2f*)outp;

    const int tid = threadIdx.x;
    const int g   = tid & 3;            // lane bits 0-1 -> shfl_xor reduction
    const int u   = (tid >> 2) & 3;     // output channel / phase1 axis
    const int sl  = tid >> 4;           // site within block
    const int s   = blockIdx.x * SPB + sl;

    // ---- issue phase-1 x loads FIRST so they overlap staging + barrier
    v2f uc[9], wc[9];
    {
        const v2f* up = x2 + (s * 8 + u) * 9;
        #pragma unroll
        for (int e = 0; e < 9; e++) uc[e] = up[e];
    }
    {
        const int sn = neigh(s, u);
        const v2f* wp = x2 + (sn * 8 + 4 + g) * 9;
        #pragma unroll
        for (int e = 0; e < 9; e++) wc[e] = wp[e];
    }

    // ---- stage packed weights to LDS (cross-wave consumers -> needs barrier)
    {
        const int u_ = tid >> 6, g_ = (tid >> 4) & 3, w_ = tid & 15;
        const float* wu_ = wgt + u_ * 297;
        wpk[(u_ * 4 + g_) * 17 + w_] =
            make_float4(wu_[g_ * 33 + w_],       wu_[g_ * 33 + 16 + w_],
                        wu_[(4 + g_) * 33 + w_], wu_[(4 + g_) * 33 + 16 + w_]);
        if (tid < 64){
            const int uu = tid >> 4, ww = tid & 15;
            const float* w8 = wgt + uu * 297 + 264;   // [u][8][*]
            wpk8[uu * 17 + ww] = make_float2(w8[ww], w8[16 + ww]);
        }
    }
    // the ONLY block-wide barrier: weight visibility. All waves reach it fast;
    // the vmcnt drain it forces covers our own uc/wc loads (needed right after).
    __syncthreads();

    // ============ phase 1: one transport per thread: t[u*4+g] = U_u W_g(s+u^) U_u^+
    {
        // T1 = U * W
        v2f t1[9];
        #pragma unroll
        for (int r = 0; r < 3; r++){
            #pragma unroll
            for (int k = 0; k < 3; k++){
                v2f acc = zero2();
                #pragma unroll
                for (int j = 0; j < 3; j++){
                    v2f a_ = uc[r*3+j], b_ = wc[j*3+k];
                    acc = pkfma(spl(a_.x), b_, acc);
                    acc = pkfma(np(a_.y), swp(b_), acc);
                }
                t1[r*3+k] = acc;
            }
        }
        // T = T1 * U^+ : T[r,k] = sum_j T1[r,j] * conj(U[k,j]); b128 writes
        v2f tt[9];
        #pragma unroll
        for (int r = 0; r < 3; r++){
            #pragma unroll
            for (int k = 0; k < 3; k++){
                v2f acc = zero2();
                #pragma unroll
                for (int j = 0; j < 3; j++){
                    v2f a_ = t1[r*3+j], b_ = uc[k*3+j];
                    acc = pkfma(pn(a_.x), b_, acc);
                    acc = pkfma(spl(a_.y), swp(b_), acc);
                }
                tt[r*3+k] = acc;
            }
        }
        v2f* dst = &lt[sl * TS2_SITE + (u * 4 + g) * TS_TILE];
        float4* dst4 = (float4*)dst;
        dst4[0] = make_float4(tt[0].x, tt[0].y, tt[1].x, tt[1].y);
        dst4[1] = make_float4(tt[2].x, tt[2].y, tt[3].x, tt[3].y);
        dst4[2] = make_float4(tt[4].x, tt[4].y, tt[5].x, tt[5].y);
        dst4[3] = make_float4(tt[6].x, tt[6].y, tt[7].x, tt[7].y);
        dst[8] = tt[8];
    }

    // pass-through copy of u channels from the already-loaded uc registers
    if (g == 1){
        v2f* dst = o2 + (s * 8 + u) * 9;
        #pragma unroll
        for (int e = 0; e < 9; e++) dst[e] = uc[e];
    }

    // ---- wave-local fence: tiles of site sl are produced and consumed within
    // ONE wave, so no s_barrier needed — just drain our own ds_writes.
    // memory clobber orders the LDS ops; sched_barrier pins reg-only ops (rule #18).
    asm volatile("s_waitcnt lgkmcnt(0)" ::: "memory");
    __builtin_amdgcn_sched_barrier(0);

    // ============ phase 2 ============
    // w=32 identity scalars straight from global (L2-hot; consumed only in the
    // epilogue, so latency is fully hidden under the main loop)
    const float* wub = wgt + u * 297;
    const float wA32 = wub[g * 33 + 32];
    const float wB32 = wub[(4 + g) * 33 + 32];
    const float w832 = wub[296];

    v2f M1[9], M2[9];
    #pragma unroll
    for (int e = 0; e < 9; e++){ M1[e] = zero2(); M2[e] = zero2(); }

    const v2f* tbase = &lt[sl * TS2_SITE];
    const int ug17 = (u * 4 + g) * 17;

    // ---- main loop: M1/M2 only; w16 uniform across lanes (broadcast LDS reads)
    // one b128 weight read/iter; unroll 2 so iter k FMAs cover iter k+1 loads
    #pragma unroll 2
    for (int w16 = 0; w16 < 16; w16++){
        v2f tc[9];
        load_tile(tc, tbase + w16 * TS_TILE);
        const float4 wq = wpk[ug17 + w16];
        const float a1 = wq.x, b1 = wq.y, a2 = wq.z, b2 = wq.w;
        #pragma unroll
        for (int i = 0; i < 3; i++){
            #pragma unroll
            for (int j = 0; j < 3; j++){
                const int e = i*3+j, eT = j*3+i;
                M1[e] = pkfma(spl(a1), tc[e],  M1[e]);
                M1[e] = pkfma(pn(b1),  tc[eT], M1[e]);
                M2[e] = pkfma(spl(a2), tc[e],  M2[e]);
                M2[e] = pkfma(pn(b2),  tc[eT], M2[e]);
            }
        }
    }

    // ---- cc: v=8 share over this thread's own quarter (w16 = 4g+it)
    v2f cc[9];
    #pragma unroll
    for (int e = 0; e < 9; e++) cc[e] = zero2();
    #pragma unroll 2
    for (int it = 0; it < 4; it++){
        const int w16 = g * 4 + it;
        v2f tc[9];
        load_tile(tc, tbase + w16 * TS_TILE);
        const float2 w8 = wpk8[u * 17 + w16];
        const float c8 = w8.x, d8 = w8.y;
        #pragma unroll
        for (int i = 0; i < 3; i++){
            #pragma unroll
            for (int j = 0; j < 3; j++){
                const int e = i*3+j, eT = j*3+i;
                cc[e] = pkfma(spl(c8), tc[e],  cc[e]);
                cc[e] = pkfma(pn(d8),  tc[eT], cc[e]);
            }
        }
    }

    // ---- identity (w=32) contributions to the diagonals
    {
        M1[0].x += wA32; M1[4].x += wA32; M1[8].x += wA32;
        M2[0].x += wB32; M2[4].x += wB32; M2[8].x += wB32;
        if (g == 0){
            cc[0].x += w832; cc[4].x += w832; cc[8].x += w832;
        }
    }

    // ---- wg loaded late (R12: early-issue neutral; late keeps loop pressure low)
    v2f wg[9];
    {
        const v2f* wp = x2 + (s * 8 + 4 + g) * 9;
        #pragma unroll
        for (int e = 0; e < 9; e++) wg[e] = wp[e];
    }

    // ---- epilogue: cc += w[g] @ M1 + w[g]^+ @ M2
    #pragma unroll
    for (int i = 0; i < 3; i++){
        #pragma unroll
        for (int k = 0; k < 3; k++){
            v2f acc = cc[i*3+k];
            #pragma unroll
            for (int j = 0; j < 3; j++){
                v2f a_ = wg[i*3+j];
                v2f m  = M1[j*3+k];
                acc = pkfma(spl(a_.x), m,      acc);   // (ax*mr, ax*mi)
                acc = pkfma(np(a_.y),  swp(m), acc);   // (-ay*mi, ay*mr)
            }
            #pragma unroll
            for (int j = 0; j < 3; j++){
                v2f b_ = wg[j*3+i];                    // conj-transpose source
                v2f m  = M2[j*3+k];
                acc = pkfma(spl(b_.x), m,      acc);   // (bx*mr, bx*mi)
                acc = pkfma(pn(b_.y),  swp(m), acc);   // (by*mi, -by*mr)
            }
            cc[i*3+k] = acc;
        }
    }

    // --- reduce partials over g (lane bits 0-1) and store
    #pragma unroll
    for (int e = 0; e < 9; e++){
        cc[e].x += __shfl_xor(cc[e].x, 1);
        cc[e].x += __shfl_xor(cc[e].x, 2);
        cc[e].y += __shfl_xor(cc[e].y, 1);
        cc[e].y += __shfl_xor(cc[e].y, 2);
    }
    if (g == 0){
        v2f* dst = o2 + (s * 8 + 4 + u) * 9;
        #pragma unroll
        for (int e = 0; e < 9; e++) dst[e] = cc[e];
    }
}

extern "C" void kernel_launch(void* const* d_in, const int* in_sizes, int n_in,
                              void* d_out, int out_size, void* d_ws, size_t ws_size,
                              hipStream_t stream)
{
    const float* x = (const float*)d_in[0];
    const float* w = (const float*)d_in[1];
    float* out = (float*)d_out;
    dim3 grid(NSITES / SPB);
    dim3 block(TPB);
    hipLaunchKernelGGL(gcm_fused, grid, block, 0, stream, x, w, out);
}